// Round 8
// baseline (183.580 us; speedup 1.0000x reference)
//
#include <hip/hip_runtime.h>

#define L 4096
#define LMASK 4095
#define NCELL (L * L)

typedef float f32x2 __attribute__((ext_vector_type(2)));
typedef float f32x4 __attribute__((ext_vector_type(4)));
typedef int   i32x2 __attribute__((ext_vector_type(2)));

__global__ __launch_bounds__(256) void spgg_qlearn_kernel(
    const int*    __restrict__ type_t,     // (L,L) int32, 0/1
    const f32x4*  __restrict__ qtab,       // (N,2,2) f32 -> vec4 per cell
    const float*  __restrict__ rnd,        // (N,2) f32 (tie-break only)
    const i32x2*  __restrict__ rtype2,     // (L,L) int32 0/1, as pairs
    const f32x2*  __restrict__ eps2,       // (L,L) f32, as pairs
    f32x2*        __restrict__ out_type2,  // (L,L) f32, as pairs
    f32x4*        __restrict__ out_q,      // (N,2,2) f32
    f32x2*        __restrict__ out_prof2)  // (L,L) f32, as pairs
{
    const i32x2* __restrict__ T2 = (const i32x2*)type_t;

    const int p = blockIdx.x * 256 + threadIdx.x;  // pair index, < 2^23
    const int i = p << 1;                          // cell index (even)
    const int r = i >> 12;
    const int c = i & LMASK;                       // even column

    // i32x2-row bases (pair index): row' << 11
    const int R0  = r << 11;
    const int Rm1 = ((r - 1) & LMASK) << 11;
    const int Rp1 = ((r + 1) & LMASK) << 11;
    const int Rm2 = ((r - 2) & LMASK) << 11;
    const int Rp2 = ((r + 2) & LMASK) << 11;
    const int Pc   = c >> 1;                       // pair col of (c, c+1)
    const int Pm   = ((c - 2) & LMASK) >> 1;       // pair col of (c-2, c-1)
    const int Pp   = ((c + 2) & LMASK) >> 1;       // pair col of (c+2, c+3)

    // ---- 11 int2 stencil loads (all independent -> max MLP) ----
    const i32x2 a   = T2[R0  + Pm];   // (c-2, c-1) row r
    const i32x2 b   = T2[R0  + Pc];   // (c,   c+1) row r
    const i32x2 d   = T2[R0  + Pp];   // (c+2, c+3) row r
    const i32x2 am1 = T2[Rm1 + Pm];
    const i32x2 bm1 = T2[Rm1 + Pc];
    const i32x2 dm1 = T2[Rm1 + Pp];
    const i32x2 ap1 = T2[Rp1 + Pm];
    const i32x2 bp1 = T2[Rp1 + Pc];
    const i32x2 dp1 = T2[Rp1 + Pp];
    const i32x2 bm2 = T2[Rm2 + Pc];
    const i32x2 bp2 = T2[Rp2 + Pc];

    // Single-use streams: nontemporal (keep L2 for reused type rows)
    f32x4 q0 = __builtin_nontemporal_load(&qtab[i]);
    f32x4 q1 = __builtin_nontemporal_load(&qtab[i + 1]);
    const f32x2 e2 = __builtin_nontemporal_load(&eps2[p]);
    const i32x2 rt = __builtin_nontemporal_load(&rtype2[p]);

    // 13-point stencil == neigh5(neigh5(coop)), weights {5,2(cross),2(diag),1(far)}
    // cell0 = col c:   cross {bm1.x,bp1.x,a.y,b.y} diag {am1.y,bm1.y,ap1.y,bp1.y} far {bm2.x,bp2.x,a.x,d.x}
    // cell1 = col c+1: cross {bm1.y,bp1.y,b.x,d.x} diag {bm1.x,dm1.x,bp1.x,dp1.x} far {bm2.y,bp2.y,a.y,d.y}
    const int w0 = 5 * b.x
                 + 2 * (bm1.x + bp1.x + a.y + b.y + am1.y + bm1.y + ap1.y + bp1.y)
                 + (bm2.x + bp2.x + a.x + d.x);
    const int w1 = 5 * b.y
                 + 2 * (bm1.y + bp1.y + b.x + d.x + bm1.x + dm1.x + bp1.x + dp1.x)
                 + (bm2.y + bp2.y + a.y + d.y);

    // profit = (R/5)*W13 - 5*c   (R/5 = 0.96)
    const float prof0 = 0.96f * (float)w0 - 5.0f * (float)b.x;
    const float prof1 = 0.96f * (float)w1 - 5.0f * (float)b.y;

    // ---- per-cell epsilon-greedy + Q update ----
    const int A0 = b.x, A1 = b.y;
    const float qa00 = A0 ? q0.z : q0.x, qa01 = A0 ? q0.w : q0.y;
    const float qa10 = A1 ? q1.z : q1.x, qa11 = A1 ? q1.w : q1.y;

    int g0 = (qa01 > qa00) ? 1 : 0;
    int g1 = (qa11 > qa10) ? 1 : 0;

    // Exact ties (~1 cell in 16.7M): wave-uniform scalar branch skips the
    // rnd loads entirely -> the 134 MB stream costs ~0 traffic, ~0 stalls.
    const bool t0 = (qa00 == qa01), t1 = (qa10 == qa11);
    if (__any(t0 || t1)) {
        f32x2 rv0, rv1;
        asm volatile("global_load_dwordx2 %0, %2, off\n\t"
                     "global_load_dwordx2 %1, %3, off\n\t"
                     "s_waitcnt vmcnt(0)"
                     : "=v"(rv0), "=v"(rv1)
                     : "v"(rnd + 2 * (long)i), "v"(rnd + 2 * (long)i + 2));
        if (t0) g0 = (rv0.y > rv0.x) ? 1 : 0;
        if (t1) g1 = (rv1.y > rv1.x) ? 1 : 0;
    }

    const int B0 = (e2.x >= 0.02f) ? g0 : rt.x;
    const int B1 = (e2.y >= 0.02f) ? g1 : rt.y;

    // max_a' Q[B][a'] from ORIGINAL table; update Q[A][B]
    const float m0 = B0 ? fmaxf(q0.z, q0.w) : fmaxf(q0.x, q0.y);
    const float m1 = B1 ? fmaxf(q1.z, q1.w) : fmaxf(q1.x, q1.y);

    const int ab0 = A0 * 2 + B0;
    const int ab1 = A1 * 2 + B1;
    const float qab0 = (ab0 == 0) ? q0.x : (ab0 == 1) ? q0.y : (ab0 == 2) ? q0.z : q0.w;
    const float qab1 = (ab1 == 0) ? q1.x : (ab1 == 1) ? q1.y : (ab1 == 2) ? q1.z : q1.w;
    const float u0 = 0.2f * qab0 + 0.8f * (prof0 + 0.8f * m0);
    const float u1 = 0.2f * qab1 + 0.8f * (prof1 + 0.8f * m1);

    q0.x = (ab0 == 0) ? u0 : q0.x;  q0.y = (ab0 == 1) ? u0 : q0.y;
    q0.z = (ab0 == 2) ? u0 : q0.z;  q0.w = (ab0 == 3) ? u0 : q0.w;
    q1.x = (ab1 == 0) ? u1 : q1.x;  q1.y = (ab1 == 1) ? u1 : q1.y;
    q1.z = (ab1 == 2) ? u1 : q1.z;  q1.w = (ab1 == 3) ? u1 : q1.w;

    // ---- nontemporal streaming stores ----
    f32x2 ot; ot.x = (float)B0; ot.y = (float)B1;
    f32x2 pr; pr.x = prof0;     pr.y = prof1;
    __builtin_nontemporal_store(ot, &out_type2[p]);
    __builtin_nontemporal_store(q0, &out_q[i]);
    __builtin_nontemporal_store(q1, &out_q[i + 1]);
    __builtin_nontemporal_store(pr, &out_prof2[p]);
}

extern "C" void kernel_launch(void* const* d_in, const int* in_sizes, int n_in,
                              void* d_out, int out_size, void* d_ws, size_t ws_size,
                              hipStream_t stream) {
    const int*    type_t = (const int*)d_in[0];
    const f32x4*  qtab   = (const f32x4*)d_in[1];
    const float*  rnd    = (const float*)d_in[2];
    const i32x2*  rtype2 = (const i32x2*)d_in[3];
    const f32x2*  eps2   = (const f32x2*)d_in[4];

    float* out      = (float*)d_out;
    f32x2* o_type2  = (f32x2*)out;                        // N
    f32x4* o_q      = (f32x4*)(out + NCELL);              // 4N
    f32x2* o_prof2  = (f32x2*)(out + 5 * (size_t)NCELL);  // N

    // 2 cells/thread: 32768 blocks x 256 threads. 8 blocks/row keeps
    // vertically-adjacent rows on the same XCD (8 % 8 == 0).
    spgg_qlearn_kernel<<<NCELL / 512, 256, 0, stream>>>(
        type_t, qtab, rnd, rtype2, eps2, o_type2, o_q, o_prof2);
}